// Round 26
// baseline (176.956 us; speedup 1.0000x reference)
//
#include <hip/hip_runtime.h>
#include <hip/hip_bf16.h>

#define F0 512
#define F1 128
#define F2 40

#define NRP 12800   // nodes per histogram partition
#define G_SL 128    // edge slices (512 blocks = 2/CU: hist/place latency hiding)

typedef __attribute__((ext_vector_type(8))) short bf16x8;
typedef __attribute__((ext_vector_type(4))) float f32x4;

__device__ inline ushort f2bf(float f) {
    union { float f; uint u; } v; v.f = f;
    uint u = v.u;
    uint r = u + 0x7fffu + ((u >> 16) & 1u);   // RNE
    return (ushort)(r >> 16);
}

#define CVT2(dst, a, b) { __hip_bfloat162 _t2 = __float22bfloat162_rn(make_float2(a, b)); __builtin_memcpy(&dst, &_t2, 4); }

// ---------------- pass 1: per-slice histograms + fused W1/W2 preconvert ----------------
__global__ __launch_bounds__(1024)
void hist_kernel(const int* __restrict__ src, const int* __restrict__ dst,
                 uchar* __restrict__ Gsrc, uchar* __restrict__ Gdst,
                 const float* __restrict__ W1, ushort* __restrict__ Wt,
                 const float* __restrict__ W2, ushort* __restrict__ W2t, int n, int E) {
    if (blockIdx.x < (F0 * F1) / 1024) {
        int idx = blockIdx.x * 1024 + threadIdx.x;
        int k = idx >> 7, nn = idx & 127;
        Wt[nn * F0 + k] = f2bf(W1[idx]);
    }
    if (blockIdx.x == 64) {
        for (int i = threadIdx.x; i < F1 * F2; i += 1024) {
            int k = i / F2, c = i % F2;     // W2[k][c]
            W2t[c * F1 + k] = f2bf(W2[i]);  // W2t[c][k]
        }
    }
    __shared__ uint cs[NRP / 2];
    __shared__ uint cd[NRP / 2];
    const int p = blockIdx.x / G_SL;
    const int g = blockIdx.x % G_SL;
    const int base = p * NRP;
    for (int i = threadIdx.x; i < NRP / 2; i += 1024) { cs[i] = 0; cd[i] = 0; }
    __syncthreads();
    const int Epg = (E + G_SL - 1) / G_SL;
    const int e0 = g * Epg;
    const int e1 = min(E, e0 + Epg);
    for (int i = e0 + (int)threadIdx.x; i < e1; i += 1024) {
        int s = src[i], d = dst[i];
        unsigned so = (unsigned)(s - base);
        unsigned dd = (unsigned)(d - base);
        if (so < (unsigned)NRP) atomicAdd(&cs[so >> 1], 1u << ((so & 1) * 16));
        if (dd < (unsigned)NRP) atomicAdd(&cd[dd >> 1], 1u << ((dd & 1) * 16));
    }
    __syncthreads();
    const int lim = min(NRP, n - base);
    for (int i = threadIdx.x; i < lim; i += 1024) {
        uint pcs = cs[i >> 1], pcd = cd[i >> 1];
        int sh = (i & 1) * 16;
        Gsrc[(size_t)g * n + base + i] = (uchar)((pcs >> sh) & 0xffu);
        Gdst[(size_t)g * n + base + i] = (uchar)((pcd >> sh) & 0xffu);
    }
}

// ---------------- pass 2: degree sums + norms + per-256-block inclusive scan ----------------
__global__ __launch_bounds__(256)
void scanA_kernel(const uchar* __restrict__ Gsrc, const uchar* __restrict__ Gdst,
                  float* __restrict__ norm_src, float* __restrict__ norm_dst,
                  int* __restrict__ row_off, int* __restrict__ bsum, int n) {
    __shared__ int sm[256];
    int i = blockIdx.x * 256 + threadIdx.x;
    int s = 0, d = 0;
    if (i < n) {
#pragma unroll
        for (int g = 0; g < G_SL; g++) {
            s += Gsrc[(size_t)g * n + i];
            d += Gdst[(size_t)g * n + i];
        }
        norm_src[i] = s > 0 ? rsqrtf((float)s) : 0.f;
        norm_dst[i] = d > 0 ? rsqrtf((float)d) : 0.f;
    }
    sm[threadIdx.x] = (i < n) ? d : 0;
    __syncthreads();
    for (int off = 1; off < 256; off <<= 1) {
        int t = (threadIdx.x >= (unsigned)off) ? sm[threadIdx.x - off] : 0;
        __syncthreads();
        sm[threadIdx.x] += t;
        __syncthreads();
    }
    if (i < n) row_off[i + 1] = sm[threadIdx.x];   // raw: in-block inclusive
    if (threadIdx.x == 255) bsum[blockIdx.x] = sm[255];
}

// ---------------- pass 3: finalize row_off (global exclusive) + per-slice start offsets ----------------
__global__ __launch_bounds__(256)
void finalize_kernel(int* __restrict__ row_off, const int* __restrict__ bsum,
                     const uchar* __restrict__ Gdst, int* __restrict__ Goff, int n) {
    __shared__ int sm[256];
    const int b = blockIdx.x;
    const int t = threadIdx.x;
    sm[t] = (t < b) ? bsum[t] : 0;
    __syncthreads();
#pragma unroll
    for (int off = 128; off > 0; off >>= 1) {
        if (t < off) sm[t] += sm[t + off];
        __syncthreads();
    }
    const int excl = sm[0];
    const int v = b * 256 + t;
    if (v >= n) return;
    int raw = row_off[v];
    int start = excl + ((t == 0) ? 0 : raw);
    if (v == n - 1) {
        int rawn = row_off[n];
        row_off[n] = excl + rawn;
    }
    row_off[v] = start;
    int run = start;
#pragma unroll
    for (int g = 0; g < G_SL; g++) {
        size_t idx = (size_t)g * n + v;
        Goff[idx] = run;
        run += Gdst[idx];
    }
}

// ---------------- FUSED: edge placement + GEMM1 (role-split grid, PLACE FIRST) ----------------
#define BM 64

union SmemU {
    int cur[NRP];        // 51.2KB (place role)
    char Al[2][8192];    // 16KB   (gemm role)
};

#define ISSUE(kt, buf) {                                                               \
    __builtin_amdgcn_global_load_lds(                                                  \
        (const __attribute__((address_space(1))) void*)(gsrc_base + (kt) * 32),        \
        (__attribute__((address_space(3))) void*)(&smu.Al[buf][tid * 16]),             \
        16, 0, 0); }

#define LOADB(k0, b) { b = *reinterpret_cast<const bf16x8*>(bp + (k0)); }

#define MKFRAG(dst, mi, bufp) {                                                        \
    const int _row = (mi) * 16 + l15;                                                  \
    const char* _pr = (bufp) + _row * 128;                                             \
    float4 _pa = *reinterpret_cast<const float4*>(_pr + (((2 * lq + 0) ^ (_row & 7)) << 4)); \
    float4 _pb = *reinterpret_cast<const float4*>(_pr + (((2 * lq + 1) ^ (_row & 7)) << 4)); \
    union { uint u[4]; bf16x8 v; } _pk;                                                \
    CVT2(_pk.u[0], _pa.x, _pa.y); CVT2(_pk.u[1], _pa.z, _pa.w);                        \
    CVT2(_pk.u[2], _pb.x, _pb.y); CVT2(_pk.u[3], _pb.z, _pb.w);                        \
    dst = _pk.v; }

#define COMPUTE(buf, b) {                                                              \
    const char* _bp = &smu.Al[buf][0];                                                 \
    bf16x8 _a0, _a1, _a2, _a3;                                                         \
    MKFRAG(_a0, 0, _bp); MKFRAG(_a1, 1, _bp); MKFRAG(_a2, 2, _bp); MKFRAG(_a3, 3, _bp);\
    acc[0] = __builtin_amdgcn_mfma_f32_16x16x32_bf16(_a0, b, acc[0], 0, 0, 0);         \
    acc[1] = __builtin_amdgcn_mfma_f32_16x16x32_bf16(_a1, b, acc[1], 0, 0, 0);         \
    acc[2] = __builtin_amdgcn_mfma_f32_16x16x32_bf16(_a2, b, acc[2], 0, 0, 0);         \
    acc[3] = __builtin_amdgcn_mfma_f32_16x16x32_bf16(_a3, b, acc[3], 0, 0, 0); }

__global__ __launch_bounds__(512)
void place_gemm1_fused(const int* __restrict__ src, const int* __restrict__ dst,
                       const int* __restrict__ Goff, int* __restrict__ edge_src,
                       const float* __restrict__ x, const ushort* __restrict__ Wt,
                       const float* __restrict__ norm_src, ushort* __restrict__ h1g,
                       int n, int E, int nplace) {
    __shared__ __align__(16) SmemU smu;
    const int tid = threadIdx.x;

    if (blockIdx.x < nplace) {
        // ---------------- place role ----------------
        const int pb = blockIdx.x;
        const int p = pb / G_SL;
        const int g = pb % G_SL;
        const int base = p * NRP;
        const int lim = min(NRP, n - base);
        for (int i = tid; i < lim; i += 512)
            smu.cur[i] = Goff[(size_t)g * n + base + i];
        __syncthreads();
        const int Epg = (E + G_SL - 1) / G_SL;
        const int e0 = g * Epg;
        const int e1 = min(E, e0 + Epg);
        for (int i = e0 + tid; i < e1; i += 512) {
            int d = dst[i];
            unsigned dd = (unsigned)(d - base);
            if (dd < (unsigned)lim) {
                int pos = atomicAdd(&smu.cur[dd], 1);
                edge_src[pos] = src[i];
            }
        }
        return;
    }

    // ---------------- gemm role (R14 v6) ----------------
    const int lane = tid & 63;
    const int w = tid >> 6;            // 0..7: wave's 16-col group
    const int l15 = lane & 15;
    const int lq = lane >> 4;
    const int bm = (blockIdx.x - nplace) * BM;

    const int st_r = tid >> 3;
    const int st_c = (tid & 7) ^ (st_r & 7);
    int grow = bm + st_r;
    if (grow >= n) grow = n - 1;       // harmless duplicate, rows >= n never stored
    const float* gsrc_base = x + (size_t)grow * F0 + st_c * 4;

    const ushort* bp = Wt + (size_t)(w * 16 + l15) * F0 + lq * 8;

    f32x4 acc[4] = {};
    bf16x8 bcur, bnxt;

    ISSUE(0, 0);
    LOADB(0, bcur);
    __syncthreads();   // drains vmcnt -> tile0 resident

    for (int kg = 0; kg < 16; ++kg) {
        const int cb = kg & 1;
        if (kg < 15) {
            ISSUE(kg + 1, cb ^ 1);            // async global->LDS, no dest VGPR
            LOADB((kg + 1) * 32, bnxt);
        }
        COMPUTE(cb, bcur);
        bcur = bnxt;
        if (kg < 15) __syncthreads();         // drains tile kg+1
    }

#pragma unroll
    for (int mi = 0; mi < 4; mi++) {
        int rbase = bm + mi * 16 + lq * 4;
#pragma unroll
        for (int r = 0; r < 4; r++) {
            int row = rbase + r;
            if (row < n) {
                float ns = norm_src[row];
                h1g[(size_t)row * F1 + w * 16 + l15] = f2bf(acc[mi][r] * ns);
            }
        }
    }
}

// ---------------- FUSED Agg1 + GEMM2: h2g = (relu(agg(h1g)*nd + b1) @ W2) * ns ----------------
__global__ __launch_bounds__(256)
void agg1_gemm2_fused(const ushort* __restrict__ h1g, const int* __restrict__ row_off,
                      const int* __restrict__ edge_src, const float* __restrict__ norm_dst,
                      const float* __restrict__ b1, const ushort* __restrict__ W2t,
                      const float* __restrict__ norm_src, ushort* __restrict__ h2g, int n) {
    __shared__ __align__(16) char h1t[16 * 256];   // 16 rows x 128 bf16, slot-swizzled
    const int tid = threadIdx.x;
    const int lane = tid & 63;
    const int w = tid >> 6;            // 0..3
    const int l15 = lane & 15;
    const int lq = lane >> 4;
    const int nb0 = blockIdx.x * 16;

    // ---- phase 1: aggregate 4 nodes per wave ----
    for (int i = 0; i < 4; ++i) {
        const int r = w * 4 + i;
        const int wid = nb0 + r;
        float a0 = 0.f, a1 = 0.f;
        if (wid < n) {
            int beg = row_off[wid], end = row_off[wid + 1];
            int e = beg;
            for (; e + 7 < end; e += 8) {
                int s[8];
#pragma unroll
                for (int j = 0; j < 8; j++) s[j] = edge_src[e + j];
                uint v[8];
#pragma unroll
                for (int j = 0; j < 8; j++)
                    v[j] = *reinterpret_cast<const uint*>(&h1g[(size_t)s[j] * F1 + lane * 2]);
#pragma unroll
                for (int j = 0; j < 8; j++) {
                    a0 += __uint_as_float(v[j] << 16);
                    a1 += __uint_as_float(v[j] & 0xffff0000u);
                }
            }
            for (; e < end; ++e) {
                int s = edge_src[e];
                uint v = *reinterpret_cast<const uint*>(&h1g[(size_t)s * F1 + lane * 2]);
                a0 += __uint_as_float(v << 16);
                a1 += __uint_as_float(v & 0xffff0000u);
            }
            float nd = norm_dst[wid];
            a0 = fmaxf(a0 * nd + b1[lane * 2 + 0], 0.f);
            a1 = fmaxf(a1 * nd + b1[lane * 2 + 1], 0.f);
        }
        uint pu; CVT2(pu, a0, a1);
        const int slotp = (lane >> 2) ^ (r & 7);
        *reinterpret_cast<uint*>(h1t + r * 256 + slotp * 16 + (lane & 3) * 4) = pu;
    }
    __syncthreads();

    // ---- phase 2: 16x40 = A(16x128 LDS) @ B(W2t), waves 0..2 ----
    if (w < 3) {
        const int col = w * 16 + l15;
        const int colc = (col < F2) ? col : (F2 - 1);
        const ushort* bp = W2t + (size_t)colc * F1 + lq * 8;
        f32x4 acc = {};
#pragma unroll
        for (int kk = 0; kk < 4; ++kk) {
            const int slotp = (kk * 4 + lq) ^ (l15 & 7);
            bf16x8 a = *reinterpret_cast<const bf16x8*>(h1t + l15 * 256 + slotp * 16);
            bf16x8 b = *reinterpret_cast<const bf16x8*>(bp + kk * 32);
            acc = __builtin_amdgcn_mfma_f32_16x16x32_bf16(a, b, acc, 0, 0, 0);
        }
#pragma unroll
        for (int rr = 0; rr < 4; ++rr) {
            int node = nb0 + lq * 4 + rr;
            if (node < n && col < F2) {
                h2g[(size_t)node * F2 + col] = f2bf(acc[rr] * norm_src[node]);
            }
        }
    }
}

// ---------------- Agg2: out = segsum(h2g[src]) * norm_dst + b2, one wave per node ----------------
__global__ __launch_bounds__(256)
void agg2_kernel(const ushort* __restrict__ h2g, const int* __restrict__ row_off,
                 const int* __restrict__ edge_src, const float* __restrict__ norm_dst,
                 const float* __restrict__ b2, float* __restrict__ out, int n) {
    int wid = (blockIdx.x * blockDim.x + threadIdx.x) >> 6;
    int lane = threadIdx.x & 63;
    if (wid >= n) return;
    int beg = row_off[wid], end = row_off[wid + 1];
    float a0 = 0.f, a1 = 0.f;
    int e = beg;
    const bool act = lane < 20;
    for (; e + 7 < end; e += 8) {
        int s[8];
#pragma unroll
        for (int j = 0; j < 8; j++) s[j] = edge_src[e + j];
        if (act) {
            uint v[8];
#pragma unroll
            for (int j = 0; j < 8; j++)
                v[j] = *reinterpret_cast<const uint*>(&h2g[(size_t)s[j] * F2 + lane * 2]);
#pragma unroll
            for (int j = 0; j < 8; j++) {
                a0 += __uint_as_float(v[j] << 16);
                a1 += __uint_as_float(v[j] & 0xffff0000u);
            }
        }
    }
    for (; e < end; ++e) {
        int s = edge_src[e];
        if (act) {
            uint v = *reinterpret_cast<const uint*>(&h2g[(size_t)s * F2 + lane * 2]);
            a0 += __uint_as_float(v << 16);
            a1 += __uint_as_float(v & 0xffff0000u);
        }
    }
    if (act) {
        float nd = norm_dst[wid];
        float o0 = a0 * nd + b2[lane * 2 + 0];
        float o1 = a1 * nd + b2[lane * 2 + 1];
        *reinterpret_cast<float2*>(&out[(size_t)wid * F2 + lane * 2]) = make_float2(o0, o1);
    }
}

extern "C" void kernel_launch(void* const* d_in, const int* in_sizes, int n_in,
                              void* d_out, int out_size, void* d_ws, size_t ws_size,
                              hipStream_t stream) {
    const float* x  = (const float*)d_in[0];
    const float* W1 = (const float*)d_in[1];
    const float* b1 = (const float*)d_in[2];
    const float* W2 = (const float*)d_in[3];
    const float* b2 = (const float*)d_in[4];
    const int* src  = (const int*)d_in[5];
    const int* dst  = (const int*)d_in[6];
    float* out = (float*)d_out;

    const int n = in_sizes[0] / F0;
    const int E = in_sizes[5];
    const int nb = (n + 255) / 256;
    const int P = (n + NRP - 1) / NRP;
    const int ngemm = (n + BM - 1) / BM;
    const int nplace = P * G_SL;

    char* ws = (char*)d_ws;
    auto alloc = [&](size_t bytes) -> char* {
        char* p = ws;
        ws += (bytes + 255) & ~(size_t)255;
        return p;
    };
    int* row_off   = (int*)alloc((size_t)(n + 1) * 4);
    int* bsum      = (int*)alloc(256 * 4);
    int* edge_srcs = (int*)alloc((size_t)E * 4);
    float* norm_src_d = (float*)alloc((size_t)n * 4);
    float* norm_dst_d = (float*)alloc((size_t)n * 4);
    ushort* W1t = (ushort*)alloc((size_t)F1 * F0 * 2);
    ushort* W2t = (ushort*)alloc((size_t)F2 * F1 * 2);
    ushort* h1g = (ushort*)alloc((size_t)n * F1 * 2);       // bf16 (12.8MB)
    char*  scratch = alloc((size_t)G_SL * n * 4);           // 25.6MB multi-use region
    uchar* Gsrc = (uchar*)alloc((size_t)G_SL * n);          // 6.4MB (h1g too small to host both at G_SL=128)
    uchar* Gdst = (uchar*)alloc((size_t)G_SL * n);          // 6.4MB

    // scratch lifetimes (strictly ordered):
    //   Goff (int, 25.6MB) in scratch: finalize -> place
    //   h2g (bf16, 4MB)   in scratch: agg1_gemm2 -> agg2 (Goff dead)
    int* Goff = (int*)scratch;
    ushort* h2g = (ushort*)scratch;

    hist_kernel<<<P * G_SL, 1024, 0, stream>>>(src, dst, Gsrc, Gdst, W1, W1t, W2, W2t, n, E);
    scanA_kernel<<<nb, 256, 0, stream>>>(Gsrc, Gdst, norm_src_d, norm_dst_d, row_off, bsum, n);
    finalize_kernel<<<nb, 256, 0, stream>>>(row_off, bsum, Gdst, Goff, n);
    place_gemm1_fused<<<nplace + ngemm, 512, 0, stream>>>(
        src, dst, Goff, edge_srcs, x, W1t, norm_src_d, h1g, n, E, nplace);
    agg1_gemm2_fused<<<(n + 15) / 16, 256, 0, stream>>>(
        h1g, row_off, edge_srcs, norm_dst_d, b1, W2t, norm_src_d, h2g, n);
    agg2_kernel<<<(n + 3) / 4, 256, 0, stream>>>(h2g, row_off, edge_srcs, norm_dst_d, b2, out, n);
}

// Round 27
// 156.746 us; speedup vs baseline: 1.1289x; 1.1289x over previous
//
#include <hip/hip_runtime.h>
#include <hip/hip_bf16.h>

#define F0 512
#define F1 128
#define F2 40

#define NRP 12800   // nodes per histogram partition
#define G_SL 64     // edge slices

typedef __attribute__((ext_vector_type(8))) short bf16x8;
typedef __attribute__((ext_vector_type(4))) float f32x4;

__device__ inline ushort f2bf(float f) {
    union { float f; uint u; } v; v.f = f;
    uint u = v.u;
    uint r = u + 0x7fffu + ((u >> 16) & 1u);   // RNE
    return (ushort)(r >> 16);
}

#define CVT2(dst, a, b) { __hip_bfloat162 _t2 = __float22bfloat162_rn(make_float2(a, b)); __builtin_memcpy(&dst, &_t2, 4); }

// ---------------- pass 1: per-slice histograms + fused W1/W2 preconvert ----------------
__global__ __launch_bounds__(1024)
void hist_kernel(const int* __restrict__ src, const int* __restrict__ dst,
                 uchar* __restrict__ Gsrc, uchar* __restrict__ Gdst,
                 const float* __restrict__ W1, ushort* __restrict__ Wt,
                 const float* __restrict__ W2, ushort* __restrict__ W2t, int n, int E) {
    if (blockIdx.x < (F0 * F1) / 1024) {
        int idx = blockIdx.x * 1024 + threadIdx.x;
        int k = idx >> 7, nn = idx & 127;
        Wt[nn * F0 + k] = f2bf(W1[idx]);
    }
    if (blockIdx.x == 64) {
        for (int i = threadIdx.x; i < F1 * F2; i += 1024) {
            int k = i / F2, c = i % F2;     // W2[k][c]
            W2t[c * F1 + k] = f2bf(W2[i]);  // W2t[c][k]
        }
    }
    __shared__ uint cs[NRP / 2];
    __shared__ uint cd[NRP / 2];
    const int p = blockIdx.x / G_SL;
    const int g = blockIdx.x % G_SL;
    const int base = p * NRP;
    for (int i = threadIdx.x; i < NRP / 2; i += 1024) { cs[i] = 0; cd[i] = 0; }
    __syncthreads();
    const int Epg = (E + G_SL - 1) / G_SL;
    const int e0 = g * Epg;
    const int e1 = min(E, e0 + Epg);
    for (int i = e0 + (int)threadIdx.x; i < e1; i += 1024) {
        int s = src[i], d = dst[i];
        unsigned so = (unsigned)(s - base);
        unsigned dd = (unsigned)(d - base);
        if (so < (unsigned)NRP) atomicAdd(&cs[so >> 1], 1u << ((so & 1) * 16));
        if (dd < (unsigned)NRP) atomicAdd(&cd[dd >> 1], 1u << ((dd & 1) * 16));
    }
    __syncthreads();
    const int lim = min(NRP, n - base);
    for (int i = threadIdx.x; i < lim; i += 1024) {
        uint pcs = cs[i >> 1], pcd = cd[i >> 1];
        int sh = (i & 1) * 16;
        Gsrc[(size_t)g * n + base + i] = (uchar)((pcs >> sh) & 0xffu);
        Gdst[(size_t)g * n + base + i] = (uchar)((pcd >> sh) & 0xffu);
    }
}

// ---------------- pass 2: degree sums + norms + per-256-block inclusive scan ----------------
__global__ __launch_bounds__(256)
void scanA_kernel(const uchar* __restrict__ Gsrc, const uchar* __restrict__ Gdst,
                  float* __restrict__ norm_src, float* __restrict__ norm_dst,
                  int* __restrict__ row_off, int* __restrict__ bsum, int n) {
    __shared__ int sm[256];
    int i = blockIdx.x * 256 + threadIdx.x;
    int s = 0, d = 0;
    if (i < n) {
#pragma unroll
        for (int g = 0; g < G_SL; g++) {
            s += Gsrc[(size_t)g * n + i];
            d += Gdst[(size_t)g * n + i];
        }
        norm_src[i] = s > 0 ? rsqrtf((float)s) : 0.f;
        norm_dst[i] = d > 0 ? rsqrtf((float)d) : 0.f;
    }
    sm[threadIdx.x] = (i < n) ? d : 0;
    __syncthreads();
    for (int off = 1; off < 256; off <<= 1) {
        int t = (threadIdx.x >= (unsigned)off) ? sm[threadIdx.x - off] : 0;
        __syncthreads();
        sm[threadIdx.x] += t;
        __syncthreads();
    }
    if (i < n) row_off[i + 1] = sm[threadIdx.x];   // raw: in-block inclusive
    if (threadIdx.x == 255) bsum[blockIdx.x] = sm[255];
}

// ---------------- pass 3: finalize row_off (global exclusive) + per-slice start offsets ----------------
__global__ __launch_bounds__(256)
void finalize_kernel(int* __restrict__ row_off, const int* __restrict__ bsum,
                     const uchar* __restrict__ Gdst, int* __restrict__ Goff, int n) {
    __shared__ int sm[256];
    const int b = blockIdx.x;
    const int t = threadIdx.x;
    sm[t] = (t < b) ? bsum[t] : 0;
    __syncthreads();
#pragma unroll
    for (int off = 128; off > 0; off >>= 1) {
        if (t < off) sm[t] += sm[t + off];
        __syncthreads();
    }
    const int excl = sm[0];
    const int v = b * 256 + t;
    if (v >= n) return;
    int raw = row_off[v];
    int start = excl + ((t == 0) ? 0 : raw);
    if (v == n - 1) {
        int rawn = row_off[n];
        row_off[n] = excl + rawn;
    }
    row_off[v] = start;
    int run = start;
#pragma unroll
    for (int g = 0; g < G_SL; g++) {
        size_t idx = (size_t)g * n + v;
        Goff[idx] = run;
        run += Gdst[idx];
    }
}

// ---------------- FUSED: edge placement + GEMM1 (role-split grid, PLACE FIRST) ----------------
#define BM 64

union SmemU {
    int cur[NRP];        // 51.2KB (place role)
    char Al[2][8192];    // 16KB   (gemm role)
};

#define ISSUE(kt, buf) {                                                               \
    __builtin_amdgcn_global_load_lds(                                                  \
        (const __attribute__((address_space(1))) void*)(gsrc_base + (kt) * 32),        \
        (__attribute__((address_space(3))) void*)(&smu.Al[buf][tid * 16]),             \
        16, 0, 0); }

#define LOADB(k0, b) { b = *reinterpret_cast<const bf16x8*>(bp + (k0)); }

#define MKFRAG(dst, mi, bufp) {                                                        \
    const int _row = (mi) * 16 + l15;                                                  \
    const char* _pr = (bufp) + _row * 128;                                             \
    float4 _pa = *reinterpret_cast<const float4*>(_pr + (((2 * lq + 0) ^ (_row & 7)) << 4)); \
    float4 _pb = *reinterpret_cast<const float4*>(_pr + (((2 * lq + 1) ^ (_row & 7)) << 4)); \
    union { uint u[4]; bf16x8 v; } _pk;                                                \
    CVT2(_pk.u[0], _pa.x, _pa.y); CVT2(_pk.u[1], _pa.z, _pa.w);                        \
    CVT2(_pk.u[2], _pb.x, _pb.y); CVT2(_pk.u[3], _pb.z, _pb.w);                        \
    dst = _pk.v; }

#define COMPUTE(buf, b) {                                                              \
    const char* _bp = &smu.Al[buf][0];                                                 \
    bf16x8 _a0, _a1, _a2, _a3;                                                         \
    MKFRAG(_a0, 0, _bp); MKFRAG(_a1, 1, _bp); MKFRAG(_a2, 2, _bp); MKFRAG(_a3, 3, _bp);\
    acc[0] = __builtin_amdgcn_mfma_f32_16x16x32_bf16(_a0, b, acc[0], 0, 0, 0);         \
    acc[1] = __builtin_amdgcn_mfma_f32_16x16x32_bf16(_a1, b, acc[1], 0, 0, 0);         \
    acc[2] = __builtin_amdgcn_mfma_f32_16x16x32_bf16(_a2, b, acc[2], 0, 0, 0);         \
    acc[3] = __builtin_amdgcn_mfma_f32_16x16x32_bf16(_a3, b, acc[3], 0, 0, 0); }

__global__ __launch_bounds__(512)
void place_gemm1_fused(const int* __restrict__ src, const int* __restrict__ dst,
                       const int* __restrict__ Goff, int* __restrict__ edge_src,
                       const float* __restrict__ x, const ushort* __restrict__ Wt,
                       const float* __restrict__ norm_src, ushort* __restrict__ h1g,
                       int n, int E, int nplace) {
    __shared__ __align__(16) SmemU smu;
    const int tid = threadIdx.x;

    if (blockIdx.x < nplace) {
        // ---------------- place role ----------------
        const int pb = blockIdx.x;
        const int p = pb / G_SL;
        const int g = pb % G_SL;
        const int base = p * NRP;
        const int lim = min(NRP, n - base);
        for (int i = tid; i < lim; i += 512)
            smu.cur[i] = Goff[(size_t)g * n + base + i];
        __syncthreads();
        const int Epg = (E + G_SL - 1) / G_SL;
        const int e0 = g * Epg;
        const int e1 = min(E, e0 + Epg);
        for (int i = e0 + tid; i < e1; i += 512) {
            int d = dst[i];
            unsigned dd = (unsigned)(d - base);
            if (dd < (unsigned)lim) {
                int pos = atomicAdd(&smu.cur[dd], 1);
                edge_src[pos] = src[i];
            }
        }
        return;
    }

    // ---------------- gemm role (R14 v6) ----------------
    const int lane = tid & 63;
    const int w = tid >> 6;            // 0..7: wave's 16-col group
    const int l15 = lane & 15;
    const int lq = lane >> 4;
    const int bm = (blockIdx.x - nplace) * BM;

    const int st_r = tid >> 3;
    const int st_c = (tid & 7) ^ (st_r & 7);
    int grow = bm + st_r;
    if (grow >= n) grow = n - 1;       // harmless duplicate, rows >= n never stored
    const float* gsrc_base = x + (size_t)grow * F0 + st_c * 4;

    const ushort* bp = Wt + (size_t)(w * 16 + l15) * F0 + lq * 8;

    f32x4 acc[4] = {};
    bf16x8 bcur, bnxt;

    ISSUE(0, 0);
    LOADB(0, bcur);
    __syncthreads();   // drains vmcnt -> tile0 resident

    for (int kg = 0; kg < 16; ++kg) {
        const int cb = kg & 1;
        if (kg < 15) {
            ISSUE(kg + 1, cb ^ 1);            // async global->LDS, no dest VGPR
            LOADB((kg + 1) * 32, bnxt);
        }
        COMPUTE(cb, bcur);
        bcur = bnxt;
        if (kg < 15) __syncthreads();         // drains tile kg+1
    }

#pragma unroll
    for (int mi = 0; mi < 4; mi++) {
        int rbase = bm + mi * 16 + lq * 4;
#pragma unroll
        for (int r = 0; r < 4; r++) {
            int row = rbase + r;
            if (row < n) {
                float ns = norm_src[row];
                h1g[(size_t)row * F1 + w * 16 + l15] = f2bf(acc[mi][r] * ns);
            }
        }
    }
}

// ---------------- FUSED Agg1 + GEMM2: h2g = (relu(agg(h1g)*nd + b1) @ W2) * ns ----------------
__global__ __launch_bounds__(256)
void agg1_gemm2_fused(const ushort* __restrict__ h1g, const int* __restrict__ row_off,
                      const int* __restrict__ edge_src, const float* __restrict__ norm_dst,
                      const float* __restrict__ b1, const ushort* __restrict__ W2t,
                      const float* __restrict__ norm_src, ushort* __restrict__ h2g, int n) {
    __shared__ __align__(16) char h1t[16 * 256];   // 16 rows x 128 bf16, slot-swizzled
    const int tid = threadIdx.x;
    const int lane = tid & 63;
    const int w = tid >> 6;            // 0..3
    const int l15 = lane & 15;
    const int lq = lane >> 4;
    const int nb0 = blockIdx.x * 16;

    // ---- phase 1: aggregate 4 nodes per wave ----
    for (int i = 0; i < 4; ++i) {
        const int r = w * 4 + i;
        const int wid = nb0 + r;
        float a0 = 0.f, a1 = 0.f;
        if (wid < n) {
            int beg = row_off[wid], end = row_off[wid + 1];
            int e = beg;
            for (; e + 7 < end; e += 8) {
                int s[8];
#pragma unroll
                for (int j = 0; j < 8; j++) s[j] = edge_src[e + j];
                uint v[8];
#pragma unroll
                for (int j = 0; j < 8; j++)
                    v[j] = *reinterpret_cast<const uint*>(&h1g[(size_t)s[j] * F1 + lane * 2]);
#pragma unroll
                for (int j = 0; j < 8; j++) {
                    a0 += __uint_as_float(v[j] << 16);
                    a1 += __uint_as_float(v[j] & 0xffff0000u);
                }
            }
            for (; e < end; ++e) {
                int s = edge_src[e];
                uint v = *reinterpret_cast<const uint*>(&h1g[(size_t)s * F1 + lane * 2]);
                a0 += __uint_as_float(v << 16);
                a1 += __uint_as_float(v & 0xffff0000u);
            }
            float nd = norm_dst[wid];
            a0 = fmaxf(a0 * nd + b1[lane * 2 + 0], 0.f);
            a1 = fmaxf(a1 * nd + b1[lane * 2 + 1], 0.f);
        }
        uint pu; CVT2(pu, a0, a1);
        const int slotp = (lane >> 2) ^ (r & 7);
        *reinterpret_cast<uint*>(h1t + r * 256 + slotp * 16 + (lane & 3) * 4) = pu;
    }
    __syncthreads();

    // ---- phase 2: 16x40 = A(16x128 LDS) @ B(W2t), waves 0..2 ----
    if (w < 3) {
        const int col = w * 16 + l15;
        const int colc = (col < F2) ? col : (F2 - 1);
        const ushort* bp = W2t + (size_t)colc * F1 + lq * 8;
        f32x4 acc = {};
#pragma unroll
        for (int kk = 0; kk < 4; ++kk) {
            const int slotp = (kk * 4 + lq) ^ (l15 & 7);
            bf16x8 a = *reinterpret_cast<const bf16x8*>(h1t + l15 * 256 + slotp * 16);
            bf16x8 b = *reinterpret_cast<const bf16x8*>(bp + kk * 32);
            acc = __builtin_amdgcn_mfma_f32_16x16x32_bf16(a, b, acc, 0, 0, 0);
        }
#pragma unroll
        for (int rr = 0; rr < 4; ++rr) {
            int node = nb0 + lq * 4 + rr;
            if (node < n && col < F2) {
                h2g[(size_t)node * F2 + col] = f2bf(acc[rr] * norm_src[node]);
            }
        }
    }
}

// ---------------- Agg2: out = segsum(h2g[src]) * norm_dst + b2, one wave per node ----------------
__global__ __launch_bounds__(256)
void agg2_kernel(const ushort* __restrict__ h2g, const int* __restrict__ row_off,
                 const int* __restrict__ edge_src, const float* __restrict__ norm_dst,
                 const float* __restrict__ b2, float* __restrict__ out, int n) {
    int wid = (blockIdx.x * blockDim.x + threadIdx.x) >> 6;
    int lane = threadIdx.x & 63;
    if (wid >= n) return;
    int beg = row_off[wid], end = row_off[wid + 1];
    float a0 = 0.f, a1 = 0.f;
    int e = beg;
    const bool act = lane < 20;
    for (; e + 7 < end; e += 8) {
        int s[8];
#pragma unroll
        for (int j = 0; j < 8; j++) s[j] = edge_src[e + j];
        if (act) {
            uint v[8];
#pragma unroll
            for (int j = 0; j < 8; j++)
                v[j] = *reinterpret_cast<const uint*>(&h2g[(size_t)s[j] * F2 + lane * 2]);
#pragma unroll
            for (int j = 0; j < 8; j++) {
                a0 += __uint_as_float(v[j] << 16);
                a1 += __uint_as_float(v[j] & 0xffff0000u);
            }
        }
    }
    for (; e < end; ++e) {
        int s = edge_src[e];
        if (act) {
            uint v = *reinterpret_cast<const uint*>(&h2g[(size_t)s * F2 + lane * 2]);
            a0 += __uint_as_float(v << 16);
            a1 += __uint_as_float(v & 0xffff0000u);
        }
    }
    if (act) {
        float nd = norm_dst[wid];
        float o0 = a0 * nd + b2[lane * 2 + 0];
        float o1 = a1 * nd + b2[lane * 2 + 1];
        *reinterpret_cast<float2*>(&out[(size_t)wid * F2 + lane * 2]) = make_float2(o0, o1);
    }
}

extern "C" void kernel_launch(void* const* d_in, const int* in_sizes, int n_in,
                              void* d_out, int out_size, void* d_ws, size_t ws_size,
                              hipStream_t stream) {
    const float* x  = (const float*)d_in[0];
    const float* W1 = (const float*)d_in[1];
    const float* b1 = (const float*)d_in[2];
    const float* W2 = (const float*)d_in[3];
    const float* b2 = (const float*)d_in[4];
    const int* src  = (const int*)d_in[5];
    const int* dst  = (const int*)d_in[6];
    float* out = (float*)d_out;

    const int n = in_sizes[0] / F0;
    const int E = in_sizes[5];
    const int nb = (n + 255) / 256;
    const int P = (n + NRP - 1) / NRP;
    const int ngemm = (n + BM - 1) / BM;
    const int nplace = P * G_SL;

    char* ws = (char*)d_ws;
    auto alloc = [&](size_t bytes) -> char* {
        char* p = ws;
        ws += (bytes + 255) & ~(size_t)255;
        return p;
    };
    int* row_off   = (int*)alloc((size_t)(n + 1) * 4);
    int* bsum      = (int*)alloc(256 * 4);
    int* edge_srcs = (int*)alloc((size_t)E * 4);
    float* norm_src_d = (float*)alloc((size_t)n * 4);
    float* norm_dst_d = (float*)alloc((size_t)n * 4);
    ushort* W1t = (ushort*)alloc((size_t)F1 * F0 * 2);
    ushort* W2t = (ushort*)alloc((size_t)F2 * F1 * 2);
    ushort* h1g = (ushort*)alloc((size_t)n * F1 * 2);       // bf16 (12.8MB)
    char*  scratch = alloc((size_t)G_SL * n * 4);           // 12.8MB multi-use region

    // scratch lifetimes (strictly ordered):
    //   Gsrc/Gdst (uchar, 6.4MB) alias h1g (dead before place_gemm1 writes h1g)
    //   Goff (int, 12.8MB) in scratch: finalize -> place
    //   h2g (bf16, 4MB)   in scratch: agg1_gemm2 -> agg2 (Goff dead)
    uchar* Gsrc = (uchar*)h1g;
    uchar* Gdst = Gsrc + (size_t)G_SL * n;
    int* Goff = (int*)scratch;
    ushort* h2g = (ushort*)scratch;

    hist_kernel<<<P * G_SL, 1024, 0, stream>>>(src, dst, Gsrc, Gdst, W1, W1t, W2, W2t, n, E);
    scanA_kernel<<<nb, 256, 0, stream>>>(Gsrc, Gdst, norm_src_d, norm_dst_d, row_off, bsum, n);
    finalize_kernel<<<nb, 256, 0, stream>>>(row_off, bsum, Gdst, Goff, n);
    place_gemm1_fused<<<nplace + ngemm, 512, 0, stream>>>(
        src, dst, Goff, edge_srcs, x, W1t, norm_src_d, h1g, n, E, nplace);
    agg1_gemm2_fused<<<(n + 15) / 16, 256, 0, stream>>>(
        h1g, row_off, edge_srcs, norm_dst_d, b1, W2t, norm_src_d, h2g, n);
    agg2_kernel<<<(n + 3) / 4, 256, 0, stream>>>(h2g, row_off, edge_srcs, norm_dst_d, b2, out, n);
}